// Round 6
// baseline (236.689 us; speedup 1.0000x reference)
//
#include <hip/hip_runtime.h>

typedef short bf16x8 __attribute__((ext_vector_type(8)));
typedef float f32x4 __attribute__((ext_vector_type(4)));

#define MFMA16(a, b, c) __builtin_amdgcn_mfma_f32_16x16x32_bf16(a, b, c, 0, 0, 0)

constexpr int Bn = 4, Sn = 4096, En = 1024, Hn = 128;
constexpr float CSCALE = 1.44269504089f * 0.03125f;   // log2(e) * E^-0.5

// 128-row q-tiles, chunk = 8 k-tiles. qt2 in [0,32): T2 = 2*qt2+2 k-tiles,
// nch = (qt2+4)>>2, nfull = (qt2+1)>>2 full-8 chunks, rem = T2&7 in {0,2,4,6}.
// Partial slot base (qt2 >= 4): prefix sum of nch.
__device__ inline int sbase2(int qt2) {
    int g = (qt2 - 4) >> 2, r = (qt2 - 4) & 3;
    return 2 * g * g + 6 * g + r * (g + 2);
}
constexpr int NSLOT = 140;         // sbase2(32): partial slots per batch
constexpr int SLOT2_F = 16640;     // 128*128 O + 128 m + 128 l floats

__device__ inline unsigned short f2bf(float f) {
    unsigned int u = __builtin_bit_cast(unsigned int, f);
    u += 0x7fff + ((u >> 16) & 1);
    return (unsigned short)(u >> 16);
}

__device__ inline unsigned int pk2(float a, float b) {
    unsigned int ua = __builtin_bit_cast(unsigned int, a) + 0x8000u;
    unsigned int ub = __builtin_bit_cast(unsigned int, b) + 0x8000u;
    return __builtin_amdgcn_perm(ub, ua, 0x07060302u);
}

__device__ inline void gld16(const unsigned short* g, unsigned short* l) {
    __builtin_amdgcn_global_load_lds((const __attribute__((address_space(1))) void*)g,
                                     (__attribute__((address_space(3))) void*)l, 16, 0, 0);
}

// ---------------- prep: W fp32 -> bf16, [q,k,v][h][E]; block 0 builds the static
// balanced schedule: 768 slots (bin = s&255 -> CU, z = s>>8). Items: per batch
// 120 full-8 chunks + 8 each of rem {2,4,6}; x4 batches = 576 items, 4224 dtiles.
// Bins: 0..191 {8,8}=16; 192..223 {8,8,2}=18; 224..255 {8,6,4}=18 dtiles.
__global__ __launch_bounds__(256) void prep_kernel(
    const float* __restrict__ Wk, const float* __restrict__ Wq, const float* __restrict__ Wv,
    unsigned short* __restrict__ wb, unsigned int* __restrict__ sched)
{
    int gy = blockIdx.x >> 5;
    const float* src = (gy == 0) ? Wq : (gy == 1) ? Wk : Wv;
    unsigned short* dst = wb + (size_t)gy * Hn * En;
    int t = (blockIdx.x & 31) * 256 + threadIdx.x;
    const float4* s4 = (const float4*)src;
    for (int i = 0; i < 4; ++i) {
        float4 v = s4[(size_t)t * 4 + i];
        uint2 w2 = { pk2(v.x, v.y), pk2(v.z, v.w) };
        *(uint2*)&dst[(size_t)t * 16 + i * 4] = w2;
    }
    if (blockIdx.x == 0) {
        const int bin = threadIdx.x;
        unsigned int it[3] = { 0xFFFFu, 0xFFFFu, 0xFFFFu };
        // full-8 item F in [0,480): b = F/120, j = F%120 -> walk qt2 desc over full chunks
        auto fullItem = [](int F) -> unsigned int {
            int b = F / 120, j = F % 120;
            int qt2 = 31, ch = 0;
            for (int q = 31; q >= 0; --q) {
                int nf = (q + 1) >> 2;
                if (j < nf) { qt2 = q; ch = j; break; }
                j -= nf;
            }
            return (unsigned int)(qt2 | (ch << 5) | (b << 8));
        };
        // remainder of length v (2/4/6), t in [0,32): b = t>>3, i = t&7
        auto remItem = [](int v, int t) -> unsigned int {
            int b = t >> 3, i = t & 7;
            int qt2 = 4 * i + (v >> 1) - 1;
            int ch = (qt2 + 1) >> 2;               // nfull = last chunk index
            return (unsigned int)(qt2 | (ch << 5) | (b << 8));
        };
        if (bin < 192) {
            it[0] = fullItem(2 * bin);
            it[1] = fullItem(2 * bin + 1);
        } else if (bin < 224) {
            int t2 = bin - 192;
            it[0] = fullItem(384 + 2 * t2);
            it[1] = fullItem(385 + 2 * t2);
            it[2] = remItem(2, t2);
        } else {
            int t2 = bin - 224;
            it[0] = fullItem(448 + t2);
            it[1] = remItem(6, t2);
            it[2] = remItem(4, t2);
        }
        for (int z = 0; z < 3; ++z) sched[z * 256 + bin] = it[z];
    }
}

// ---------------- fused QKV projection (unchanged R5): one pass over x ----------------
__global__ __launch_bounds__(512, 2) void proj_kernel(
    const float* __restrict__ x, const unsigned short* __restrict__ wb,
    unsigned short* __restrict__ qb, unsigned short* __restrict__ kb,
    unsigned short* __restrict__ vbT)
{
    __shared__ __align__(16) unsigned short xs[2][64][64];     // 2 x 8 KB
    __shared__ __align__(16) unsigned short wsm[2][384][64];   // 2 x 48 KB

    const int m0 = blockIdx.x * 64;
    const int tid = threadIdx.x;
    const int lane = tid & 63, wave = tid >> 6;
    const int l15 = lane & 15, quad = lane >> 4;
    const int wn = wave * 48;

    f32x4 acc[4][3] = {};
    float4 xp[2];

    auto loadx = [&](int kc) {
        for (int p2 = 0; p2 < 2; ++p2) {
            int i = p2 * 512 + tid, row = i >> 4, c4 = (i & 15) * 4;
            xp[p2] = *(const float4*)&x[(size_t)(m0 + row) * En + kc * 64 + c4];
        }
    };
    auto writex = [&](int c) {
        for (int p2 = 0; p2 < 2; ++p2) {
            int i = p2 * 512 + tid, row = i >> 4, hc = i & 15;
            uint2 w2 = { pk2(xp[p2].x, xp[p2].y), pk2(xp[p2].z, xp[p2].w) };
            *(uint2*)((char*)&xs[c][0][0] + row * 128 + (((hc >> 1) ^ (row & 7)) << 4) + ((hc & 1) << 3)) = w2;
        }
    };
    auto issueW = [&](int kc, int c) {
        for (int j = 0; j < 6; ++j) {
            int seg = (wave * 6 + j) * 1024;
            int d = seg + (lane << 4);
            int row = d >> 7, chp = (d >> 4) & 7;
            gld16(wb + (size_t)row * En + kc * 64 + ((chp ^ (row & 7)) << 3),
                  (unsigned short*)((char*)&wsm[c][0][0] + seg));
        }
    };

    loadx(0);
    issueW(0, 0);
    writex(0);
    loadx(1);

    for (int kc = 0; kc < En / 64; ++kc) {
        const int c = kc & 1;
        __syncthreads();
        if (kc + 1 < En / 64) {
            issueW(kc + 1, c ^ 1);
            writex(c ^ 1);
            int kn = (kc + 2 < En / 64) ? kc + 2 : En / 64 - 1;
            loadx(kn);
        }
        bf16x8 xf[4][2], wf[3][2];
        for (int i = 0; i < 4; ++i)
            for (int kk = 0; kk < 2; ++kk) {
                int row = i * 16 + l15;
                int chn = (kk * 4 + quad) ^ (row & 7);
                xf[i][kk] = *(const bf16x8*)((char*)&xs[c][0][0] + row * 128 + (chn << 4));
            }
        for (int j = 0; j < 3; ++j)
            for (int kk = 0; kk < 2; ++kk) {
                int row = wn + j * 16 + l15;
                int chn = (kk * 4 + quad) ^ (row & 7);
                wf[j][kk] = *(const bf16x8*)((char*)&wsm[c][0][0] + row * 128 + (chn << 4));
            }
        for (int kk = 0; kk < 2; ++kk)
            for (int i = 0; i < 4; ++i)
                for (int j = 0; j < 3; ++j)
                    acc[i][j] = MFMA16(xf[i][kk], wf[j][kk], acc[i][j]);
    }

    for (int i = 0; i < 4; ++i) {
        int rowb = m0 + i * 16 + quad * 4;
        for (int j = 0; j < 3; ++j) {
            int gcol = wn + j * 16 + l15;
            int gy = gcol >> 7, col = gcol & 127;
            if (gy == 0) {
                for (int r = 0; r < 4; ++r)
                    qb[(size_t)(rowb + r) * Hn + col] = f2bf(acc[i][j][r] * CSCALE);
            } else if (gy == 1) {
                for (int r = 0; r < 4; ++r)
                    kb[(size_t)(rowb + r) * Hn + col] = f2bf(acc[i][j][r]);
            } else {
                int bb = rowb >> 12, ss = rowb & 4095;
                uint2 w2 = { pk2(acc[i][j][0], acc[i][j][1]), pk2(acc[i][j][2], acc[i][j][3]) };
                *(uint2*)&vbT[((size_t)(bb * 128 + col)) * Sn + ss] = w2;
            }
        }
    }
}

// ---------------- attention: 128q tiles, NO K/V LDS staging, NO barriers ----------------
// K/V per batch = 1 MB each -> L1/L2-resident; staging them in LDS was pure overhead
// (176 KB LDS traffic per tile, 65% of ds_read ceiling, + 2 barriers/tile).
// Fragments now read straight from global (byte-identical values to the staged path).
// LDS = per-wave P strip only (18 KB) -> 3 blocks/CU resident; waves fully independent.
// Grid 768 = 256 bins x 3 z-slots; chunk = 8 k-tiles (576 real items).
__global__ __launch_bounds__(256, 3) void attn_kernel(
    const unsigned short* __restrict__ qb, const unsigned short* __restrict__ kb,
    const unsigned short* __restrict__ vbT, float* __restrict__ out,
    float* __restrict__ part, const unsigned int* __restrict__ sched)
{
    __shared__ unsigned short ps[4][32][72];  // per-wave P strip [q(32)][key]

    const unsigned int wi = sched[blockIdx.x];
    if (wi == 0xFFFFu) return;
    const int qt2 = (int)(wi & 31u);
    const int ch  = (int)((wi >> 5) & 7u);
    const int b   = (int)((wi >> 8) & 3u);
    const int T2  = 2 * qt2 + 2;              // total k-tiles for this q-tile
    const int nch = (qt2 + 4) >> 2;
    const int t0 = ch * 8;
    const int nloc = min(8, T2 - t0);
    const int q0 = qt2 * 128;

    const int tid = threadIdx.x;
    const int lane = tid & 63, wave = tid >> 6;
    const int l15 = lane & 15, quad = lane >> 4;

    const unsigned short* qg = qb + (size_t)(b * Sn + q0) * Hn;
    bf16x8 qf[2][4];
    for (int g = 0; g < 2; ++g)
        for (int f = 0; f < 4; ++f)
            qf[g][f] = *(const bf16x8*)&qg[(wave * 32 + g * 16 + l15) * Hn + f * 32 + quad * 8];

    f32x4 o[2][8] = {};          // O^T per group: h = t*16+quad*4+r, q = l15
    float m_r[2] = { -INFINITY, -INFINITY }, l_r[2] = { 0.f, 0.f };

    const unsigned short* kg = kb + (size_t)b * Sn * Hn;
    const unsigned short* vg = vbT + (size_t)b * 128 * Sn;

    for (int tl = 0; tl < nloc; ++tl) {
        const int gt = t0 + tl;
        const int kt0 = gt * 64;

        // S^T: A = K (from global/L1), B = Q group g; kf shared by both groups
        float u[2][4][4];
        for (int nt = 0; nt < 4; ++nt) {
            f32x4 s0 = {}, s1 = {};
            for (int kk = 0; kk < 4; ++kk) {
                bf16x8 kf = *(const bf16x8*)&kg[(size_t)(kt0 + nt * 16 + l15) * Hn + kk * 32 + quad * 8];
                s0 = MFMA16(kf, qf[0][kk], s0);
                s1 = MFMA16(kf, qf[1][kk], s1);
            }
            for (int r = 0; r < 4; ++r) { u[0][nt][r] = s0[r]; u[1][nt][r] = s1[r]; }
        }
        if (gt >= 2 * qt2) {      // diagonal tiles: mask keys > q
            int kof = (gt - 2 * qt2) * 64;
            for (int g = 0; g < 2; ++g) {
                int qq = wave * 32 + g * 16 + l15;
                for (int nt = 0; nt < 4; ++nt)
                    for (int r = 0; r < 4; ++r)
                        if (kof + nt * 16 + quad * 4 + r > qq) u[g][nt][r] = -INFINITY;
            }
        }
        // per-lane online softmax, per q-group (log2 domain; CSCALE folded into q)
        for (int g = 0; g < 2; ++g) {
            float mx = -INFINITY;
            for (int nt = 0; nt < 4; ++nt)
                for (int r = 0; r < 4; ++r) mx = fmaxf(mx, u[g][nt][r]);
            mx = fmaxf(mx, __shfl_xor(mx, 16));
            mx = fmaxf(mx, __shfl_xor(mx, 32));
            float mn = fmaxf(m_r[g], mx);
            float alpha = exp2f(m_r[g] - mn);
            m_r[g] = mn;
            float sum = 0.f;
            for (int nt = 0; nt < 4; ++nt)
                for (int r = 0; r < 4; ++r) {
                    float pv = exp2f(u[g][nt][r] - mn);
                    u[g][nt][r] = pv;
                    sum += pv;
                }
            sum += __shfl_xor(sum, 16);
            sum += __shfl_xor(sum, 32);
            l_r[g] = l_r[g] * alpha + sum;

            unsigned short* psrow = &ps[wave][g * 16 + l15][0];
            for (int nt = 0; nt < 4; ++nt) {
                uint2 w2 = { pk2(u[g][nt][0], u[g][nt][1]), pk2(u[g][nt][2], u[g][nt][3]) };
                *(uint2*)&psrow[nt * 16 + quad * 4] = w2;
            }
            for (int t = 0; t < 8; ++t) o[g][t] *= alpha;
        }

        // O^T += V^T P^T — vf from global/L1, shared by both groups (same-wave ps, no barrier)
        for (int k2 = 0; k2 < 2; ++k2) {
            bf16x8 pf0 = *(const bf16x8*)&ps[wave][0 * 16 + l15][k2 * 32 + quad * 8];
            bf16x8 pf1 = *(const bf16x8*)&ps[wave][1 * 16 + l15][k2 * 32 + quad * 8];
            for (int t = 0; t < 8; ++t) {
                bf16x8 vf = *(const bf16x8*)&vg[(size_t)(t * 16 + l15) * Sn + kt0 + k2 * 32 + quad * 8];
                o[0][t] = MFMA16(vf, pf0, o[0][t]);
                o[1][t] = MFMA16(vf, pf1, o[1][t]);
            }
        }
    }

    if (nch == 1) {
        for (int g = 0; g < 2; ++g) {
            float inv = 1.0f / l_r[g];
            float* og = out + (size_t)(b * Sn + q0 + wave * 32 + g * 16 + l15) * Hn;
            for (int t = 0; t < 8; ++t) {
                float4 st = { o[g][t][0] * inv, o[g][t][1] * inv, o[g][t][2] * inv, o[g][t][3] * inv };
                *(float4*)&og[t * 16 + quad * 4] = st;
            }
        }
    } else {
        float* P = part + (size_t)(b * NSLOT + sbase2(qt2) + ch) * SLOT2_F;
        for (int g = 0; g < 2; ++g) {
            int q = wave * 32 + g * 16 + l15;
            for (int t = 0; t < 8; ++t) {
                float4 st = { o[g][t][0], o[g][t][1], o[g][t][2], o[g][t][3] };
                *(float4*)&P[q * 128 + t * 16 + quad * 4] = st;
            }
            if (quad == 0) {
                P[16384 + q] = m_r[g];
                P[16512 + q] = l_r[g];
            }
        }
    }
}

// ---------------- merge partials for qt2 >= 4 (nch up to 8) ----------------
// grid (56, B): qt2 = 4 + bx/2, half = bx&1; 256 thr: q = half*64 + tid>>2, h0 = (tid&3)*32
__global__ __launch_bounds__(256) void merge_kernel(
    const float* __restrict__ part, float* __restrict__ out)
{
    const int qt2 = 4 + (blockIdx.x >> 1);
    const int half = blockIdx.x & 1;
    const int b = blockIdx.y;
    const int nch = (qt2 + 4) >> 2;
    const float* P0 = part + (size_t)(b * NSLOT + sbase2(qt2)) * SLOT2_F;
    const int q = half * 64 + (threadIdx.x >> 2);
    const int h0 = (threadIdx.x & 3) * 32;

    float m[8], w[8];
    float M = -INFINITY;
    for (int c = 0; c < nch; ++c) {
        m[c] = P0[(size_t)c * SLOT2_F + 16384 + q];
        M = fmaxf(M, m[c]);
    }
    float L = 0.f;
    for (int c = 0; c < nch; ++c) {
        w[c] = exp2f(m[c] - M);
        L += w[c] * P0[(size_t)c * SLOT2_F + 16512 + q];
    }
    float inv = 1.0f / L;

    float acc[32] = {};
    for (int c = 0; c < nch; ++c) {
        const float* Pq = P0 + (size_t)c * SLOT2_F + q * 128 + h0;
        for (int j = 0; j < 8; ++j) {
            float4 v = *(const float4*)&Pq[j * 4];
            acc[j * 4 + 0] += w[c] * v.x;
            acc[j * 4 + 1] += w[c] * v.y;
            acc[j * 4 + 2] += w[c] * v.z;
            acc[j * 4 + 3] += w[c] * v.w;
        }
    }
    float* og = out + (size_t)(b * Sn + qt2 * 128 + q) * Hn + h0;
    for (int j = 0; j < 8; ++j) {
        float4 st = { acc[j * 4 + 0] * inv, acc[j * 4 + 1] * inv,
                      acc[j * 4 + 2] * inv, acc[j * 4 + 3] * inv };
        *(float4*)&og[j * 4] = st;
    }
}

extern "C" void kernel_launch(void* const* d_in, const int* in_sizes, int n_in,
                              void* d_out, int out_size, void* d_ws, size_t ws_size,
                              hipStream_t stream)
{
    const float* x  = (const float*)d_in[0];
    const float* Wk = (const float*)d_in[1];
    const float* Wq = (const float*)d_in[2];
    const float* Wv = (const float*)d_in[3];
    float* out = (float*)d_out;

    unsigned short* qbuf  = (unsigned short*)d_ws;                  // 4 MB (pre-scaled)
    unsigned short* kbuf  = qbuf + (size_t)Bn * Sn * Hn;            // 4 MB
    unsigned short* vbufT = kbuf + (size_t)Bn * Sn * Hn;            // 4 MB, [b][h][s]
    unsigned short* wb    = vbufT + (size_t)Bn * Sn * Hn;           // 0.75 MB bf16 W
    unsigned int* sched   = (unsigned int*)(wb + (size_t)3 * Hn * En);  // 4 KB table
    float* part = (float*)(sched + 1024);                           // 37.3 MB partials

    prep_kernel<<<96, 256, 0, stream>>>(Wk, Wq, Wv, wb, sched);
    proj_kernel<<<256, 512, 0, stream>>>(x, wb, qbuf, kbuf, vbufT);
    attn_kernel<<<768, 256, 0, stream>>>(qbuf, kbuf, vbufT, out, part, sched);
    merge_kernel<<<dim3(56, Bn), 256, 0, stream>>>(part, out);
}

// Round 7
// 232.320 us; speedup vs baseline: 1.0188x; 1.0188x over previous
//
#include <hip/hip_runtime.h>

typedef short bf16x8 __attribute__((ext_vector_type(8)));
typedef float f32x4 __attribute__((ext_vector_type(4)));

#define MFMA16(a, b, c) __builtin_amdgcn_mfma_f32_16x16x32_bf16(a, b, c, 0, 0, 0)

constexpr int Bn = 4, Sn = 4096, En = 1024, Hn = 128;
constexpr float CSCALE = 1.44269504089f * 0.03125f;   // log2(e) * E^-0.5

// 128-row q-tiles, chunk = 8 k-tiles. qt2 in [0,32): T2 = 2*qt2+2 k-tiles,
// nch = (qt2+4)>>2, nfull = (qt2+1)>>2 full-8 chunks, rem = T2&7 in {0,2,4,6}.
// Partial slot base (qt2 >= 4): prefix sum of nch.
__device__ inline int sbase2(int qt2) {
    int g = (qt2 - 4) >> 2, r = (qt2 - 4) & 3;
    return 2 * g * g + 6 * g + r * (g + 2);
}
constexpr int NSLOT = 140;         // sbase2(32): partial slots per batch
constexpr int SLOT2_F = 16640;     // 128*128 O + 128 m + 128 l floats

__device__ inline unsigned short f2bf(float f) {
    unsigned int u = __builtin_bit_cast(unsigned int, f);
    u += 0x7fff + ((u >> 16) & 1);
    return (unsigned short)(u >> 16);
}

__device__ inline unsigned int pk2(float a, float b) {
    unsigned int ua = __builtin_bit_cast(unsigned int, a) + 0x8000u;
    unsigned int ub = __builtin_bit_cast(unsigned int, b) + 0x8000u;
    return __builtin_amdgcn_perm(ub, ua, 0x07060302u);
}

__device__ inline void gld16(const unsigned short* g, unsigned short* l) {
    __builtin_amdgcn_global_load_lds((const __attribute__((address_space(1))) void*)g,
                                     (__attribute__((address_space(3))) void*)l, 16, 0, 0);
}

// ---------------- prep: W fp32 -> bf16, [q,k,v][h][E]; block 0 builds the static
// balanced schedule: 768 slots (bin = s&255 -> CU, z = s>>8). Items: per batch
// 120 full-8 chunks + 8 each of rem {2,4,6}; x4 batches = 576 items, 4224 dtiles.
// Bins: 0..191 {8,8}=16; 192..223 {8,8,2}=18; 224..255 {8,6,4}=18 dtiles.
__global__ __launch_bounds__(256) void prep_kernel(
    const float* __restrict__ Wk, const float* __restrict__ Wq, const float* __restrict__ Wv,
    unsigned short* __restrict__ wb, unsigned int* __restrict__ sched)
{
    int gy = blockIdx.x >> 5;
    const float* src = (gy == 0) ? Wq : (gy == 1) ? Wk : Wv;
    unsigned short* dst = wb + (size_t)gy * Hn * En;
    int t = (blockIdx.x & 31) * 256 + threadIdx.x;
    const float4* s4 = (const float4*)src;
    for (int i = 0; i < 4; ++i) {
        float4 v = s4[(size_t)t * 4 + i];
        uint2 w2 = { pk2(v.x, v.y), pk2(v.z, v.w) };
        *(uint2*)&dst[(size_t)t * 16 + i * 4] = w2;
    }
    if (blockIdx.x == 0) {
        const int bin = threadIdx.x;
        unsigned int it[3] = { 0xFFFFu, 0xFFFFu, 0xFFFFu };
        // full-8 item F in [0,480): b = F/120, j = F%120 -> walk qt2 desc over full chunks
        auto fullItem = [](int F) -> unsigned int {
            int b = F / 120, j = F % 120;
            int qt2 = 31, ch = 0;
            for (int q = 31; q >= 0; --q) {
                int nf = (q + 1) >> 2;
                if (j < nf) { qt2 = q; ch = j; break; }
                j -= nf;
            }
            return (unsigned int)(qt2 | (ch << 5) | (b << 8));
        };
        // remainder of length v (2/4/6), t in [0,32): b = t>>3, i = t&7
        auto remItem = [](int v, int t) -> unsigned int {
            int b = t >> 3, i = t & 7;
            int qt2 = 4 * i + (v >> 1) - 1;
            int ch = (qt2 + 1) >> 2;               // nfull = last chunk index
            return (unsigned int)(qt2 | (ch << 5) | (b << 8));
        };
        if (bin < 192) {
            it[0] = fullItem(2 * bin);
            it[1] = fullItem(2 * bin + 1);
        } else if (bin < 224) {
            int t2 = bin - 192;
            it[0] = fullItem(384 + 2 * t2);
            it[1] = fullItem(385 + 2 * t2);
            it[2] = remItem(2, t2);
        } else {
            int t2 = bin - 224;
            it[0] = fullItem(448 + t2);
            it[1] = remItem(6, t2);
            it[2] = remItem(4, t2);
        }
        for (int z = 0; z < 3; ++z) sched[z * 256 + bin] = it[z];
    }
}

// ---------------- fused QKV projection (unchanged R5): one pass over x ----------------
__global__ __launch_bounds__(512, 2) void proj_kernel(
    const float* __restrict__ x, const unsigned short* __restrict__ wb,
    unsigned short* __restrict__ qb, unsigned short* __restrict__ kb,
    unsigned short* __restrict__ vbT)
{
    __shared__ __align__(16) unsigned short xs[2][64][64];     // 2 x 8 KB
    __shared__ __align__(16) unsigned short wsm[2][384][64];   // 2 x 48 KB

    const int m0 = blockIdx.x * 64;
    const int tid = threadIdx.x;
    const int lane = tid & 63, wave = tid >> 6;
    const int l15 = lane & 15, quad = lane >> 4;
    const int wn = wave * 48;

    f32x4 acc[4][3] = {};
    float4 xp[2];

    auto loadx = [&](int kc) {
        for (int p2 = 0; p2 < 2; ++p2) {
            int i = p2 * 512 + tid, row = i >> 4, c4 = (i & 15) * 4;
            xp[p2] = *(const float4*)&x[(size_t)(m0 + row) * En + kc * 64 + c4];
        }
    };
    auto writex = [&](int c) {
        for (int p2 = 0; p2 < 2; ++p2) {
            int i = p2 * 512 + tid, row = i >> 4, hc = i & 15;
            uint2 w2 = { pk2(xp[p2].x, xp[p2].y), pk2(xp[p2].z, xp[p2].w) };
            *(uint2*)((char*)&xs[c][0][0] + row * 128 + (((hc >> 1) ^ (row & 7)) << 4) + ((hc & 1) << 3)) = w2;
        }
    };
    auto issueW = [&](int kc, int c) {
        for (int j = 0; j < 6; ++j) {
            int seg = (wave * 6 + j) * 1024;
            int d = seg + (lane << 4);
            int row = d >> 7, chp = (d >> 4) & 7;
            gld16(wb + (size_t)row * En + kc * 64 + ((chp ^ (row & 7)) << 3),
                  (unsigned short*)((char*)&wsm[c][0][0] + seg));
        }
    };

    loadx(0);
    issueW(0, 0);
    writex(0);
    loadx(1);

    for (int kc = 0; kc < En / 64; ++kc) {
        const int c = kc & 1;
        __syncthreads();
        if (kc + 1 < En / 64) {
            issueW(kc + 1, c ^ 1);
            writex(c ^ 1);
            int kn = (kc + 2 < En / 64) ? kc + 2 : En / 64 - 1;
            loadx(kn);
        }
        bf16x8 xf[4][2], wf[3][2];
        for (int i = 0; i < 4; ++i)
            for (int kk = 0; kk < 2; ++kk) {
                int row = i * 16 + l15;
                int chn = (kk * 4 + quad) ^ (row & 7);
                xf[i][kk] = *(const bf16x8*)((char*)&xs[c][0][0] + row * 128 + (chn << 4));
            }
        for (int j = 0; j < 3; ++j)
            for (int kk = 0; kk < 2; ++kk) {
                int row = wn + j * 16 + l15;
                int chn = (kk * 4 + quad) ^ (row & 7);
                wf[j][kk] = *(const bf16x8*)((char*)&wsm[c][0][0] + row * 128 + (chn << 4));
            }
        for (int kk = 0; kk < 2; ++kk)
            for (int i = 0; i < 4; ++i)
                for (int j = 0; j < 3; ++j)
                    acc[i][j] = MFMA16(xf[i][kk], wf[j][kk], acc[i][j]);
    }

    for (int i = 0; i < 4; ++i) {
        int rowb = m0 + i * 16 + quad * 4;
        for (int j = 0; j < 3; ++j) {
            int gcol = wn + j * 16 + l15;
            int gy = gcol >> 7, col = gcol & 127;
            if (gy == 0) {
                for (int r = 0; r < 4; ++r)
                    qb[(size_t)(rowb + r) * Hn + col] = f2bf(acc[i][j][r] * CSCALE);
            } else if (gy == 1) {
                for (int r = 0; r < 4; ++r)
                    kb[(size_t)(rowb + r) * Hn + col] = f2bf(acc[i][j][r]);
            } else {
                int bb = rowb >> 12, ss = rowb & 4095;
                uint2 w2 = { pk2(acc[i][j][0], acc[i][j][1]), pk2(acc[i][j][2], acc[i][j][3]) };
                *(uint2*)&vbT[((size_t)(bb * 128 + col)) * Sn + ss] = w2;
            }
        }
    }
}

// ---------------- attention: 128q staged tiles + chunk-8 balanced schedule ----------
// R4 body (LDS-staged K/V, reg prefetch, frags shared by both 16-row q-groups per
// wave: ~1.8x less LDS traffic per unit work than the 64q version) combined with
// R6 schedule (768 slots = 3 blocks/CU residency, bins of 16-18 dtiles).
// LDS 51.5 KB -> 3 blocks/CU. R6's latency lesson: keep LDS staging (bulk async
// amortization); never feed MFMA operands straight from global.
__global__ __launch_bounds__(256, 3) void attn_kernel(
    const unsigned short* __restrict__ qb, const unsigned short* __restrict__ kb,
    const unsigned short* __restrict__ vbT, float* __restrict__ out,
    float* __restrict__ part, const unsigned int* __restrict__ sched)
{
    __shared__ unsigned short ks[64][132];    // K tile [key][h]
    __shared__ unsigned short vt[128][68];    // V^T [h][key]
    __shared__ unsigned short ps[4][32][72];  // per-wave P strip [q(32)][key]

    const unsigned int wi = sched[blockIdx.x];
    if (wi == 0xFFFFu) return;
    const int qt2 = (int)(wi & 31u);
    const int ch  = (int)((wi >> 5) & 7u);
    const int b   = (int)((wi >> 8) & 3u);
    const int T2  = 2 * qt2 + 2;              // total k-tiles for this q-tile
    const int nch = (qt2 + 4) >> 2;
    const int t0 = ch * 8;
    const int nloc = min(8, T2 - t0);
    const int q0 = qt2 * 128;

    const int tid = threadIdx.x;
    const int lane = tid & 63, wave = tid >> 6;
    const int l15 = lane & 15, quad = lane >> 4;

    const unsigned short* qg = qb + (size_t)(b * Sn + q0) * Hn;
    bf16x8 qf[2][4];
    for (int g = 0; g < 2; ++g)
        for (int f = 0; f < 4; ++f)
            qf[g][f] = *(const bf16x8*)&qg[(wave * 32 + g * 16 + l15) * Hn + f * 32 + quad * 8];

    f32x4 o[2][8] = {};          // O^T per group: h = t*16+quad*4+r, q = l15
    float m_r[2] = { -INFINITY, -INFINITY }, l_r[2] = { 0.f, 0.f };

    const unsigned short* kg = kb + (size_t)b * Sn * Hn;
    const unsigned short* vg = vbT + (size_t)b * 128 * Sn;

    bf16x8 kreg[4], vreg[4];
    auto loadKV = [&](int gt) {
        int kt0 = gt * 64;
        for (int p4 = 0; p4 < 4; ++p4) {
            int i = p4 * 256 + tid;
            kreg[p4] = *(const bf16x8*)&kg[(size_t)(kt0 + (i >> 4)) * Hn + (i & 15) * 8];
            vreg[p4] = *(const bf16x8*)&vg[(size_t)(i >> 3) * Sn + kt0 + (i & 7) * 8];
        }
    };

    loadKV(t0);
    for (int tl = 0; tl < nloc; ++tl) {
        const int gt = t0 + tl;
        for (int p4 = 0; p4 < 4; ++p4) {
            int i = p4 * 256 + tid;
            *(bf16x8*)&ks[i >> 4][(i & 15) * 8] = kreg[p4];
            *(bf16x8*)&vt[i >> 3][(i & 7) * 8] = vreg[p4];
        }
        __syncthreads();
        if (tl + 1 < nloc) loadKV(gt + 1);

        // S^T: A = K (m=key), B = Q group g. kf read once, used by BOTH groups.
        float u[2][4][4];
        for (int nt = 0; nt < 4; ++nt) {
            f32x4 s0 = {}, s1 = {};
            for (int kk = 0; kk < 4; ++kk) {
                bf16x8 kf = *(const bf16x8*)&ks[nt * 16 + l15][kk * 32 + quad * 8];
                s0 = MFMA16(kf, qf[0][kk], s0);
                s1 = MFMA16(kf, qf[1][kk], s1);
            }
            for (int r = 0; r < 4; ++r) { u[0][nt][r] = s0[r]; u[1][nt][r] = s1[r]; }
        }
        if (gt >= 2 * qt2) {      // diagonal tiles: mask keys > q
            int kof = (gt - 2 * qt2) * 64;
            for (int g = 0; g < 2; ++g) {
                int qq = wave * 32 + g * 16 + l15;
                for (int nt = 0; nt < 4; ++nt)
                    for (int r = 0; r < 4; ++r)
                        if (kof + nt * 16 + quad * 4 + r > qq) u[g][nt][r] = -INFINITY;
            }
        }
        // per-lane online softmax, per q-group (log2 domain; CSCALE folded into q)
        for (int g = 0; g < 2; ++g) {
            float mx = -INFINITY;
            for (int nt = 0; nt < 4; ++nt)
                for (int r = 0; r < 4; ++r) mx = fmaxf(mx, u[g][nt][r]);
            mx = fmaxf(mx, __shfl_xor(mx, 16));
            mx = fmaxf(mx, __shfl_xor(mx, 32));
            float mn = fmaxf(m_r[g], mx);
            float alpha = exp2f(m_r[g] - mn);
            m_r[g] = mn;
            float sum = 0.f;
            for (int nt = 0; nt < 4; ++nt)
                for (int r = 0; r < 4; ++r) {
                    float pv = exp2f(u[g][nt][r] - mn);
                    u[g][nt][r] = pv;
                    sum += pv;
                }
            sum += __shfl_xor(sum, 16);
            sum += __shfl_xor(sum, 32);
            l_r[g] = l_r[g] * alpha + sum;

            unsigned short* psrow = &ps[wave][g * 16 + l15][0];
            for (int nt = 0; nt < 4; ++nt) {
                uint2 w2 = { pk2(u[g][nt][0], u[g][nt][1]), pk2(u[g][nt][2], u[g][nt][3]) };
                *(uint2*)&psrow[nt * 16 + quad * 4] = w2;
            }
            for (int t = 0; t < 8; ++t) o[g][t] *= alpha;
        }

        // O^T += V^T P^T — vf read once, used by BOTH groups (same-wave ps, no barrier)
        for (int k2 = 0; k2 < 2; ++k2) {
            bf16x8 pf0 = *(const bf16x8*)&ps[wave][0 * 16 + l15][k2 * 32 + quad * 8];
            bf16x8 pf1 = *(const bf16x8*)&ps[wave][1 * 16 + l15][k2 * 32 + quad * 8];
            for (int t = 0; t < 8; ++t) {
                bf16x8 vf = *(const bf16x8*)&vt[t * 16 + l15][k2 * 32 + quad * 8];
                o[0][t] = MFMA16(vf, pf0, o[0][t]);
                o[1][t] = MFMA16(vf, pf1, o[1][t]);
            }
        }
        __syncthreads();   // protect ks/vt before next iteration's writes
    }

    if (nch == 1) {
        for (int g = 0; g < 2; ++g) {
            float inv = 1.0f / l_r[g];
            float* og = out + (size_t)(b * Sn + q0 + wave * 32 + g * 16 + l15) * Hn;
            for (int t = 0; t < 8; ++t) {
                float4 st = { o[g][t][0] * inv, o[g][t][1] * inv, o[g][t][2] * inv, o[g][t][3] * inv };
                *(float4*)&og[t * 16 + quad * 4] = st;
            }
        }
    } else {
        float* P = part + (size_t)(b * NSLOT + sbase2(qt2) + ch) * SLOT2_F;
        for (int g = 0; g < 2; ++g) {
            int q = wave * 32 + g * 16 + l15;
            for (int t = 0; t < 8; ++t) {
                float4 st = { o[g][t][0], o[g][t][1], o[g][t][2], o[g][t][3] };
                *(float4*)&P[q * 128 + t * 16 + quad * 4] = st;
            }
            if (quad == 0) {
                P[16384 + q] = m_r[g];
                P[16512 + q] = l_r[g];
            }
        }
    }
}

// ---------------- merge partials for qt2 >= 4 (nch up to 8) ----------------
// grid (56, B): qt2 = 4 + bx/2, half = bx&1; 256 thr: q = half*64 + tid>>2, h0 = (tid&3)*32
__global__ __launch_bounds__(256) void merge_kernel(
    const float* __restrict__ part, float* __restrict__ out)
{
    const int qt2 = 4 + (blockIdx.x >> 1);
    const int half = blockIdx.x & 1;
    const int b = blockIdx.y;
    const int nch = (qt2 + 4) >> 2;
    const float* P0 = part + (size_t)(b * NSLOT + sbase2(qt2)) * SLOT2_F;
    const int q = half * 64 + (threadIdx.x >> 2);
    const int h0 = (threadIdx.x & 3) * 32;

    float m[8], w[8];
    float M = -INFINITY;
    for (int c = 0; c < nch; ++c) {
        m[c] = P0[(size_t)c * SLOT2_F + 16384 + q];
        M = fmaxf(M, m[c]);
    }
    float L = 0.f;
    for (int c = 0; c < nch; ++c) {
        w[c] = exp2f(m[c] - M);
        L += w[c] * P0[(size_t)c * SLOT2_F + 16512 + q];
    }
    float inv = 1.0f / L;

    float acc[32] = {};
    for (int c = 0; c < nch; ++c) {
        const float* Pq = P0 + (size_t)c * SLOT2_F + q * 128 + h0;
        for (int j = 0; j < 8; ++j) {
            float4 v = *(const float4*)&Pq[j * 4];
            acc[j * 4 + 0] += w[c] * v.x;
            acc[j * 4 + 1] += w[c] * v.y;
            acc[j * 4 + 2] += w[c] * v.z;
            acc[j * 4 + 3] += w[c] * v.w;
        }
    }
    float* og = out + (size_t)(b * Sn + qt2 * 128 + q) * Hn + h0;
    for (int j = 0; j < 8; ++j) {
        float4 st = { acc[j * 4 + 0] * inv, acc[j * 4 + 1] * inv,
                      acc[j * 4 + 2] * inv, acc[j * 4 + 3] * inv };
        *(float4*)&og[j * 4] = st;
    }
}

extern "C" void kernel_launch(void* const* d_in, const int* in_sizes, int n_in,
                              void* d_out, int out_size, void* d_ws, size_t ws_size,
                              hipStream_t stream)
{
    const float* x  = (const float*)d_in[0];
    const float* Wk = (const float*)d_in[1];
    const float* Wq = (const float*)d_in[2];
    const float* Wv = (const float*)d_in[3];
    float* out = (float*)d_out;

    unsigned short* qbuf  = (unsigned short*)d_ws;                  // 4 MB (pre-scaled)
    unsigned short* kbuf  = qbuf + (size_t)Bn * Sn * Hn;            // 4 MB
    unsigned short* vbufT = kbuf + (size_t)Bn * Sn * Hn;            // 4 MB, [b][h][s]
    unsigned short* wb    = vbufT + (size_t)Bn * Sn * Hn;           // 0.75 MB bf16 W
    unsigned int* sched   = (unsigned int*)(wb + (size_t)3 * Hn * En);  // 4 KB table
    float* part = (float*)(sched + 1024);                           // 37.3 MB partials

    prep_kernel<<<96, 256, 0, stream>>>(Wk, Wq, Wv, wb, sched);
    proj_kernel<<<256, 512, 0, stream>>>(x, wb, qbuf, kbuf, vbufT);
    attn_kernel<<<768, 256, 0, stream>>>(qbuf, kbuf, vbufT, out, part, sched);
    merge_kernel<<<dim3(56, Bn), 256, 0, stream>>>(part, out);
}

// Round 8
// 182.423 us; speedup vs baseline: 1.2975x; 1.2735x over previous
//
#include <hip/hip_runtime.h>

typedef short bf16x8 __attribute__((ext_vector_type(8)));
typedef float f32x4 __attribute__((ext_vector_type(4)));

#define MFMA16(a, b, c) __builtin_amdgcn_mfma_f32_16x16x32_bf16(a, b, c, 0, 0, 0)

constexpr int Bn = 4, Sn = 4096, En = 1024, Hn = 128;
constexpr float CSCALE = 1.44269504089f * 0.03125f;   // log2(e) * E^-0.5

// 128-row q-tiles, chunk = 8 k-tiles. qt2 in [0,32): T2 = 2*qt2+2 k-tiles,
// nch = (qt2+4)>>2, nfull = (qt2+1)>>2 full-8 chunks, rem = T2&7 in {0,2,4,6}.
// Partial slot base (qt2 >= 4): prefix sum of nch.
__device__ inline int sbase2(int qt2) {
    int g = (qt2 - 4) >> 2, r = (qt2 - 4) & 3;
    return 2 * g * g + 6 * g + r * (g + 2);
}
constexpr int NSLOT = 140;         // sbase2(32): partial slots per batch
constexpr int SLOT2_F = 16640;     // 128*128 O + 128 m + 128 l floats

__device__ inline unsigned short f2bf(float f) {
    unsigned int u = __builtin_bit_cast(unsigned int, f);
    u += 0x7fff + ((u >> 16) & 1);
    return (unsigned short)(u >> 16);
}

__device__ inline unsigned int pk2(float a, float b) {
    unsigned int ua = __builtin_bit_cast(unsigned int, a) + 0x8000u;
    unsigned int ub = __builtin_bit_cast(unsigned int, b) + 0x8000u;
    return __builtin_amdgcn_perm(ub, ua, 0x07060302u);
}

__device__ inline void gld16(const unsigned short* g, unsigned short* l) {
    __builtin_amdgcn_global_load_lds((const __attribute__((address_space(1))) void*)g,
                                     (__attribute__((address_space(3))) void*)l, 16, 0, 0);
}

// ---------------- prep: W fp32 -> bf16, [q,k,v][h][E]; block 0 builds the static
// balanced schedule: 768 slots (bin = s&255 -> CU, z = s>>8). Items: per batch
// 120 full-8 chunks + 8 each of rem {2,4,6}; x4 batches = 576 items, 4224 dtiles.
// Bins: 0..191 {8,8}=16; 192..223 {8,8,2}=18; 224..255 {8,6,4}=18 dtiles.
__global__ __launch_bounds__(256) void prep_kernel(
    const float* __restrict__ Wk, const float* __restrict__ Wq, const float* __restrict__ Wv,
    unsigned short* __restrict__ wb, unsigned int* __restrict__ sched)
{
    int gy = blockIdx.x >> 5;
    const float* src = (gy == 0) ? Wq : (gy == 1) ? Wk : Wv;
    unsigned short* dst = wb + (size_t)gy * Hn * En;
    int t = (blockIdx.x & 31) * 256 + threadIdx.x;
    const float4* s4 = (const float4*)src;
    for (int i = 0; i < 4; ++i) {
        float4 v = s4[(size_t)t * 4 + i];
        uint2 w2 = { pk2(v.x, v.y), pk2(v.z, v.w) };
        *(uint2*)&dst[(size_t)t * 16 + i * 4] = w2;
    }
    if (blockIdx.x == 0) {
        const int bin = threadIdx.x;
        unsigned int it[3] = { 0xFFFFu, 0xFFFFu, 0xFFFFu };
        // full-8 item F in [0,480): b = F/120, j = F%120 -> walk qt2 desc over full chunks
        auto fullItem = [](int F) -> unsigned int {
            int b = F / 120, j = F % 120;
            int qt2 = 31, ch = 0;
            for (int q = 31; q >= 0; --q) {
                int nf = (q + 1) >> 2;
                if (j < nf) { qt2 = q; ch = j; break; }
                j -= nf;
            }
            return (unsigned int)(qt2 | (ch << 5) | (b << 8));
        };
        // remainder of length v (2/4/6), t in [0,32): b = t>>3, i = t&7
        auto remItem = [](int v, int t) -> unsigned int {
            int b = t >> 3, i = t & 7;
            int qt2 = 4 * i + (v >> 1) - 1;
            int ch = (qt2 + 1) >> 2;               // nfull = last chunk index
            return (unsigned int)(qt2 | (ch << 5) | (b << 8));
        };
        if (bin < 192) {
            it[0] = fullItem(2 * bin);
            it[1] = fullItem(2 * bin + 1);
        } else if (bin < 224) {
            int t2 = bin - 192;
            it[0] = fullItem(384 + 2 * t2);
            it[1] = fullItem(385 + 2 * t2);
            it[2] = remItem(2, t2);
        } else {
            int t2 = bin - 224;
            it[0] = fullItem(448 + t2);
            it[1] = remItem(6, t2);
            it[2] = remItem(4, t2);
        }
        for (int z = 0; z < 3; ++z) sched[z * 256 + bin] = it[z];
    }
}

// ---------------- fused QKV projection (unchanged R5): one pass over x ----------------
__global__ __launch_bounds__(512, 2) void proj_kernel(
    const float* __restrict__ x, const unsigned short* __restrict__ wb,
    unsigned short* __restrict__ qb, unsigned short* __restrict__ kb,
    unsigned short* __restrict__ vbT)
{
    __shared__ __align__(16) unsigned short xs[2][64][64];     // 2 x 8 KB
    __shared__ __align__(16) unsigned short wsm[2][384][64];   // 2 x 48 KB

    const int m0 = blockIdx.x * 64;
    const int tid = threadIdx.x;
    const int lane = tid & 63, wave = tid >> 6;
    const int l15 = lane & 15, quad = lane >> 4;
    const int wn = wave * 48;

    f32x4 acc[4][3] = {};
    float4 xp[2];

    auto loadx = [&](int kc) {
        for (int p2 = 0; p2 < 2; ++p2) {
            int i = p2 * 512 + tid, row = i >> 4, c4 = (i & 15) * 4;
            xp[p2] = *(const float4*)&x[(size_t)(m0 + row) * En + kc * 64 + c4];
        }
    };
    auto writex = [&](int c) {
        for (int p2 = 0; p2 < 2; ++p2) {
            int i = p2 * 512 + tid, row = i >> 4, hc = i & 15;
            uint2 w2 = { pk2(xp[p2].x, xp[p2].y), pk2(xp[p2].z, xp[p2].w) };
            *(uint2*)((char*)&xs[c][0][0] + row * 128 + (((hc >> 1) ^ (row & 7)) << 4) + ((hc & 1) << 3)) = w2;
        }
    };
    auto issueW = [&](int kc, int c) {
        for (int j = 0; j < 6; ++j) {
            int seg = (wave * 6 + j) * 1024;
            int d = seg + (lane << 4);
            int row = d >> 7, chp = (d >> 4) & 7;
            gld16(wb + (size_t)row * En + kc * 64 + ((chp ^ (row & 7)) << 3),
                  (unsigned short*)((char*)&wsm[c][0][0] + seg));
        }
    };

    loadx(0);
    issueW(0, 0);
    writex(0);
    loadx(1);

    for (int kc = 0; kc < En / 64; ++kc) {
        const int c = kc & 1;
        __syncthreads();
        if (kc + 1 < En / 64) {
            issueW(kc + 1, c ^ 1);
            writex(c ^ 1);
            int kn = (kc + 2 < En / 64) ? kc + 2 : En / 64 - 1;
            loadx(kn);
        }
        bf16x8 xf[4][2], wf[3][2];
        for (int i = 0; i < 4; ++i)
            for (int kk = 0; kk < 2; ++kk) {
                int row = i * 16 + l15;
                int chn = (kk * 4 + quad) ^ (row & 7);
                xf[i][kk] = *(const bf16x8*)((char*)&xs[c][0][0] + row * 128 + (chn << 4));
            }
        for (int j = 0; j < 3; ++j)
            for (int kk = 0; kk < 2; ++kk) {
                int row = wn + j * 16 + l15;
                int chn = (kk * 4 + quad) ^ (row & 7);
                wf[j][kk] = *(const bf16x8*)((char*)&wsm[c][0][0] + row * 128 + (chn << 4));
            }
        for (int kk = 0; kk < 2; ++kk)
            for (int i = 0; i < 4; ++i)
                for (int j = 0; j < 3; ++j)
                    acc[i][j] = MFMA16(xf[i][kk], wf[j][kk], acc[i][j]);
    }

    for (int i = 0; i < 4; ++i) {
        int rowb = m0 + i * 16 + quad * 4;
        for (int j = 0; j < 3; ++j) {
            int gcol = wn + j * 16 + l15;
            int gy = gcol >> 7, col = gcol & 127;
            if (gy == 0) {
                for (int r = 0; r < 4; ++r)
                    qb[(size_t)(rowb + r) * Hn + col] = f2bf(acc[i][j][r] * CSCALE);
            } else if (gy == 1) {
                for (int r = 0; r < 4; ++r)
                    kb[(size_t)(rowb + r) * Hn + col] = f2bf(acc[i][j][r]);
            } else {
                int bb = rowb >> 12, ss = rowb & 4095;
                uint2 w2 = { pk2(acc[i][j][0], acc[i][j][1]), pk2(acc[i][j][2], acc[i][j][3]) };
                *(uint2*)&vbT[((size_t)(bb * 128 + col)) * Sn + ss] = w2;
            }
        }
    }
}

// ---------------- attention: 128q staged tiles + chunk-8 balanced schedule ----------
// R4 body (LDS-staged K/V, reg prefetch, frags shared by both 16-row q-groups per
// wave) + R6 schedule (768 slots, bins of 16-18 dtiles, bin = s&255 -> CU).
// __launch_bounds__(256, 2): the body needs ~190-200 live (V+A)GPRs; the (256,3)
// bound in R7 capped the unified file at ~170/wave and spilled accumulators to
// scratch (WRITE_SIZE 187 MB, MfmaUtil 0.2%). 2 waves/SIMD = 2 resident
// blocks/CU (LDS would allow 3; VGPR is the binding limit — that's fine, the
// third queued block starts when a slot frees and per-CU work stays balanced).
__global__ __launch_bounds__(256, 2) void attn_kernel(
    const unsigned short* __restrict__ qb, const unsigned short* __restrict__ kb,
    const unsigned short* __restrict__ vbT, float* __restrict__ out,
    float* __restrict__ part, const unsigned int* __restrict__ sched)
{
    __shared__ unsigned short ks[64][132];    // K tile [key][h]
    __shared__ unsigned short vt[128][68];    // V^T [h][key]
    __shared__ unsigned short ps[4][32][72];  // per-wave P strip [q(32)][key]

    const unsigned int wi = sched[blockIdx.x];
    if (wi == 0xFFFFu) return;
    const int qt2 = (int)(wi & 31u);
    const int ch  = (int)((wi >> 5) & 7u);
    const int b   = (int)((wi >> 8) & 3u);
    const int T2  = 2 * qt2 + 2;              // total k-tiles for this q-tile
    const int nch = (qt2 + 4) >> 2;
    const int t0 = ch * 8;
    const int nloc = min(8, T2 - t0);
    const int q0 = qt2 * 128;

    const int tid = threadIdx.x;
    const int lane = tid & 63, wave = tid >> 6;
    const int l15 = lane & 15, quad = lane >> 4;

    const unsigned short* qg = qb + (size_t)(b * Sn + q0) * Hn;
    bf16x8 qf[2][4];
    for (int g = 0; g < 2; ++g)
        for (int f = 0; f < 4; ++f)
            qf[g][f] = *(const bf16x8*)&qg[(wave * 32 + g * 16 + l15) * Hn + f * 32 + quad * 8];

    f32x4 o[2][8] = {};          // O^T per group: h = t*16+quad*4+r, q = l15
    float m_r[2] = { -INFINITY, -INFINITY }, l_r[2] = { 0.f, 0.f };

    const unsigned short* kg = kb + (size_t)b * Sn * Hn;
    const unsigned short* vg = vbT + (size_t)b * 128 * Sn;

    bf16x8 kreg[4], vreg[4];
    auto loadKV = [&](int gt) {
        int kt0 = gt * 64;
        for (int p4 = 0; p4 < 4; ++p4) {
            int i = p4 * 256 + tid;
            kreg[p4] = *(const bf16x8*)&kg[(size_t)(kt0 + (i >> 4)) * Hn + (i & 15) * 8];
            vreg[p4] = *(const bf16x8*)&vg[(size_t)(i >> 3) * Sn + kt0 + (i & 7) * 8];
        }
    };

    loadKV(t0);
    for (int tl = 0; tl < nloc; ++tl) {
        const int gt = t0 + tl;
        for (int p4 = 0; p4 < 4; ++p4) {
            int i = p4 * 256 + tid;
            *(bf16x8*)&ks[i >> 4][(i & 15) * 8] = kreg[p4];
            *(bf16x8*)&vt[i >> 3][(i & 7) * 8] = vreg[p4];
        }
        __syncthreads();
        if (tl + 1 < nloc) loadKV(gt + 1);

        // S^T: A = K (m=key), B = Q group g. kf read once, used by BOTH groups.
        float u[2][4][4];
        for (int nt = 0; nt < 4; ++nt) {
            f32x4 s0 = {}, s1 = {};
            for (int kk = 0; kk < 4; ++kk) {
                bf16x8 kf = *(const bf16x8*)&ks[nt * 16 + l15][kk * 32 + quad * 8];
                s0 = MFMA16(kf, qf[0][kk], s0);
                s1 = MFMA16(kf, qf[1][kk], s1);
            }
            for (int r = 0; r < 4; ++r) { u[0][nt][r] = s0[r]; u[1][nt][r] = s1[r]; }
        }
        if (gt >= 2 * qt2) {      // diagonal tiles: mask keys > q
            int kof = (gt - 2 * qt2) * 64;
            for (int g = 0; g < 2; ++g) {
                int qq = wave * 32 + g * 16 + l15;
                for (int nt = 0; nt < 4; ++nt)
                    for (int r = 0; r < 4; ++r)
                        if (kof + nt * 16 + quad * 4 + r > qq) u[g][nt][r] = -INFINITY;
            }
        }
        // per-lane online softmax, per q-group (log2 domain; CSCALE folded into q)
        for (int g = 0; g < 2; ++g) {
            float mx = -INFINITY;
            for (int nt = 0; nt < 4; ++nt)
                for (int r = 0; r < 4; ++r) mx = fmaxf(mx, u[g][nt][r]);
            mx = fmaxf(mx, __shfl_xor(mx, 16));
            mx = fmaxf(mx, __shfl_xor(mx, 32));
            float mn = fmaxf(m_r[g], mx);
            float alpha = exp2f(m_r[g] - mn);
            m_r[g] = mn;
            float sum = 0.f;
            for (int nt = 0; nt < 4; ++nt)
                for (int r = 0; r < 4; ++r) {
                    float pv = exp2f(u[g][nt][r] - mn);
                    u[g][nt][r] = pv;
                    sum += pv;
                }
            sum += __shfl_xor(sum, 16);
            sum += __shfl_xor(sum, 32);
            l_r[g] = l_r[g] * alpha + sum;

            unsigned short* psrow = &ps[wave][g * 16 + l15][0];
            for (int nt = 0; nt < 4; ++nt) {
                uint2 w2 = { pk2(u[g][nt][0], u[g][nt][1]), pk2(u[g][nt][2], u[g][nt][3]) };
                *(uint2*)&psrow[nt * 16 + quad * 4] = w2;
            }
            for (int t = 0; t < 8; ++t) o[g][t] *= alpha;
        }

        // O^T += V^T P^T — vf read once, used by BOTH groups (same-wave ps, no barrier)
        for (int k2 = 0; k2 < 2; ++k2) {
            bf16x8 pf0 = *(const bf16x8*)&ps[wave][0 * 16 + l15][k2 * 32 + quad * 8];
            bf16x8 pf1 = *(const bf16x8*)&ps[wave][1 * 16 + l15][k2 * 32 + quad * 8];
            for (int t = 0; t < 8; ++t) {
                bf16x8 vf = *(const bf16x8*)&vt[t * 16 + l15][k2 * 32 + quad * 8];
                o[0][t] = MFMA16(vf, pf0, o[0][t]);
                o[1][t] = MFMA16(vf, pf1, o[1][t]);
            }
        }
        __syncthreads();   // protect ks/vt before next iteration's writes
    }

    if (nch == 1) {
        for (int g = 0; g < 2; ++g) {
            float inv = 1.0f / l_r[g];
            float* og = out + (size_t)(b * Sn + q0 + wave * 32 + g * 16 + l15) * Hn;
            for (int t = 0; t < 8; ++t) {
                float4 st = { o[g][t][0] * inv, o[g][t][1] * inv, o[g][t][2] * inv, o[g][t][3] * inv };
                *(float4*)&og[t * 16 + quad * 4] = st;
            }
        }
    } else {
        float* P = part + (size_t)(b * NSLOT + sbase2(qt2) + ch) * SLOT2_F;
        for (int g = 0; g < 2; ++g) {
            int q = wave * 32 + g * 16 + l15;
            for (int t = 0; t < 8; ++t) {
                float4 st = { o[g][t][0], o[g][t][1], o[g][t][2], o[g][t][3] };
                *(float4*)&P[q * 128 + t * 16 + quad * 4] = st;
            }
            if (quad == 0) {
                P[16384 + q] = m_r[g];
                P[16512 + q] = l_r[g];
            }
        }
    }
}

// ---------------- merge partials for qt2 >= 4 (nch up to 8) ----------------
// grid (56, B): qt2 = 4 + bx/2, half = bx&1; 256 thr: q = half*64 + tid>>2, h0 = (tid&3)*32
__global__ __launch_bounds__(256) void merge_kernel(
    const float* __restrict__ part, float* __restrict__ out)
{
    const int qt2 = 4 + (blockIdx.x >> 1);
    const int half = blockIdx.x & 1;
    const int b = blockIdx.y;
    const int nch = (qt2 + 4) >> 2;
    const float* P0 = part + (size_t)(b * NSLOT + sbase2(qt2)) * SLOT2_F;
    const int q = half * 64 + (threadIdx.x >> 2);
    const int h0 = (threadIdx.x & 3) * 32;

    float m[8], w[8];
    float M = -INFINITY;
    for (int c = 0; c < nch; ++c) {
        m[c] = P0[(size_t)c * SLOT2_F + 16384 + q];
        M = fmaxf(M, m[c]);
    }
    float L = 0.f;
    for (int c = 0; c < nch; ++c) {
        w[c] = exp2f(m[c] - M);
        L += w[c] * P0[(size_t)c * SLOT2_F + 16512 + q];
    }
    float inv = 1.0f / L;

    float acc[32] = {};
    for (int c = 0; c < nch; ++c) {
        const float* Pq = P0 + (size_t)c * SLOT2_F + q * 128 + h0;
        for (int j = 0; j < 8; ++j) {
            float4 v = *(const float4*)&Pq[j * 4];
            acc[j * 4 + 0] += w[c] * v.x;
            acc[j * 4 + 1] += w[c] * v.y;
            acc[j * 4 + 2] += w[c] * v.z;
            acc[j * 4 + 3] += w[c] * v.w;
        }
    }
    float* og = out + (size_t)(b * Sn + qt2 * 128 + q) * Hn + h0;
    for (int j = 0; j < 8; ++j) {
        float4 st = { acc[j * 4 + 0] * inv, acc[j * 4 + 1] * inv,
                      acc[j * 4 + 2] * inv, acc[j * 4 + 3] * inv };
        *(float4*)&og[j * 4] = st;
    }
}

extern "C" void kernel_launch(void* const* d_in, const int* in_sizes, int n_in,
                              void* d_out, int out_size, void* d_ws, size_t ws_size,
                              hipStream_t stream)
{
    const float* x  = (const float*)d_in[0];
    const float* Wk = (const float*)d_in[1];
    const float* Wq = (const float*)d_in[2];
    const float* Wv = (const float*)d_in[3];
    float* out = (float*)d_out;

    unsigned short* qbuf  = (unsigned short*)d_ws;                  // 4 MB (pre-scaled)
    unsigned short* kbuf  = qbuf + (size_t)Bn * Sn * Hn;            // 4 MB
    unsigned short* vbufT = kbuf + (size_t)Bn * Sn * Hn;            // 4 MB, [b][h][s]
    unsigned short* wb    = vbufT + (size_t)Bn * Sn * Hn;           // 0.75 MB bf16 W
    unsigned int* sched   = (unsigned int*)(wb + (size_t)3 * Hn * En);  // 4 KB table
    float* part = (float*)(sched + 1024);                           // 37.3 MB partials

    prep_kernel<<<96, 256, 0, stream>>>(Wk, Wq, Wv, wb, sched);
    proj_kernel<<<256, 512, 0, stream>>>(x, wb, qbuf, kbuf, vbufT);
    attn_kernel<<<768, 256, 0, stream>>>(qbuf, kbuf, vbufT, out, part, sched);
    merge_kernel<<<dim3(56, Bn), 256, 0, stream>>>(part, out);
}